// Round 9
// baseline (931.104 us; speedup 1.0000x reference)
//
#include <hip/hip_runtime.h>

#define NN    200000
#define F_IN  128
#define HID   35
#define NCLS  10
#define LD1   36      // f32 acc1 row entries (144B)
#define NB2   512     // dest buckets
#define NPB2  391     // nodes per bucket (ceil(200000/512))
#define CAP2  6912    // bucket capacity: mean 6250 + 8.4 sigma
#define NCH   7       // source chunks: src>>15, 0..6 (2MB of hs1A each)
#define BINS  (NCH*NPB2)   // 2737 sort bins
#define BINP  2816    // padded (256*11)
#define PB    11      // bins per thread in sort scan
#define EPT   32      // edges per thread in k_bucket
#define E_TOT 3200000

// bf16 helpers (manual RNE)
static __device__ inline unsigned short f2bf(float f) {
    unsigned u = __float_as_uint(f);
    u = (u + 0x7FFFu + ((u >> 16) & 1u)) >> 16;
    return (unsigned short)u;
}
static __device__ inline unsigned pk2(float a, float b) {
    return (unsigned)f2bf(a) | ((unsigned)f2bf(b) << 16);
}
static __device__ inline float bf2f(unsigned short h) {
    return __uint_as_float((unsigned)h << 16);
}
static __device__ inline float bflo(unsigned u) { return __uint_as_float(u << 16); }
static __device__ inline float bfhi(unsigned u) { return __uint_as_float(u & 0xFFFF0000u); }

// ---------- bucket build ----------

__global__ void k_initcur(int* __restrict__ gcur) {
    int t = threadIdx.x;
    if (t < NB2) gcur[t] = t * CAP2;
}

// scatter edges into 391-node destination buckets; payload = src | local_col<<18
__global__ __launch_bounds__(256)
void k_bucket(const int* __restrict__ row, const int* __restrict__ col, int E,
              int* __restrict__ gcur, unsigned* __restrict__ bkt) {
    __shared__ int hist[NB2];
    __shared__ int basev[NB2];
    int t = threadIdx.x;
    long e0 = (long)blockIdx.x * (256 * EPT);
    for (int i = t; i < NB2; i += 256) hist[i] = 0;
    __syncthreads();
    int cols[EPT];
#pragma unroll
    for (int i = 0; i < EPT; ++i) {
        long e = e0 + (long)i * 256 + t;
        if (e < E) {
            int c = col[e];
            cols[i] = c;
            atomicAdd(&hist[c / NPB2], 1);
        } else cols[i] = -1;
    }
    __syncthreads();
    for (int i = t; i < NB2; i += 256) {
        int h = hist[i];
        basev[i] = (h > 0) ? atomicAdd(&gcur[i], h) : 0;
        hist[i] = 0;   // reuse as local cursor
    }
    __syncthreads();
#pragma unroll
    for (int i = 0; i < EPT; ++i) {
        int c = cols[i];
        if (c >= 0) {
            long e = e0 + (long)i * 256 + t;
            int r = row[e];
            int b = c / NPB2;
            int lc = c - b * NPB2;
            int pos = basev[b] + atomicAdd(&hist[b], 1);
            if (pos < (b + 1) * CAP2) bkt[pos] = (unsigned)r | ((unsigned)lc << 18);
        }
    }
}

// per-bucket LDS counting sort by (src_chunk, local_dst); emits dinv. In-place.
__global__ __launch_bounds__(256)
void k_sort(unsigned* __restrict__ bkt, const int* __restrict__ gcur,
            float* __restrict__ dinv, int n) {
    __shared__ unsigned est[CAP2];   // 27.6 KB
    __shared__ int hist[BINP];       // 11 KB
    __shared__ int cur[BINP];        // 11 KB
    __shared__ int sc[257];
    int b = blockIdx.x, t = threadIdx.x;
    int ec = gcur[b] - b * CAP2;
    if (ec > CAP2) ec = CAP2;
    unsigned* ep = bkt + (size_t)b * CAP2;
    for (int i = t; i < BINP; i += 256) hist[i] = 0;
    __syncthreads();
    for (int e = t; e < ec; e += 256) {
        unsigned p = ep[e];
        est[e] = p;
        int lc = p >> 18;
        int src = p & 0x3FFFF;
        atomicAdd(&hist[(src >> 15) * NPB2 + lc], 1);
    }
    __syncthreads();
    // dinv from per-node degree (sum over chunks)
    for (int lc = t; lc < NPB2; lc += 256) {
        int node = b * NPB2 + lc;
        if (node < n) {
            int deg = 0;
#pragma unroll
            for (int c = 0; c < NCH; ++c) deg += hist[c * NPB2 + lc];
            dinv[node] = rsqrtf((float)(deg + 1));   // +1 self loop
        }
    }
    // exclusive scan over BINP bins: serial-per-thread + block scan
    int s0 = 0;
#pragma unroll
    for (int k = 0; k < PB; ++k) {
        int i = t * PB + k;
        if (i < BINP) { cur[i] = s0; s0 += hist[i]; }
    }
    sc[t] = s0;
    __syncthreads();
    for (int d = 1; d < 256; d <<= 1) {
        int add = (t >= d) ? sc[t - d] : 0;
        __syncthreads();
        sc[t] += add;
        __syncthreads();
    }
    int off = sc[t] - s0;   // exclusive block offset
#pragma unroll
    for (int k = 0; k < PB; ++k) {
        int i = t * PB + k;
        if (i < BINP) cur[i] += off;
    }
    __syncthreads();
    for (int e = t; e < ec; e += 256) {
        unsigned p = est[e];
        int lc = p >> 18;
        int src = p & 0x3FFFF;
        int pos = atomicAdd(&cur[(src >> 15) * NPB2 + lc], 1);
        ep[pos] = p;   // keep (src, lc) payload, now chunk-major order
    }
}

// ---------- layer 1 ----------

// hs1A[i][0..31] / hs1B[i][0..3] = bf16( dinv[i] * (x@W1)[i][:] )
__global__ void k_gemm1(const float* __restrict__ x, const float* __restrict__ W1,
                        const float* __restrict__ dinv,
                        unsigned short* __restrict__ hs1A,
                        unsigned short* __restrict__ hs1B, int n) {
    int i = blockIdx.x * blockDim.x + threadIdx.x;
    if (i >= n) return;
    float acc[HID];
#pragma unroll
    for (int j = 0; j < HID; ++j) acc[j] = 0.f;
    const float4* xr = (const float4*)(x + (size_t)i * F_IN);
    for (int k4 = 0; k4 < F_IN / 4; ++k4) {
        float4 xv = xr[k4];
        const float* w = W1 + (size_t)(k4 * 4) * HID;
#pragma unroll
        for (int j = 0; j < HID; ++j)
            acc[j] += xv.x * w[j] + xv.y * w[HID + j] + xv.z * w[2 * HID + j] + xv.w * w[3 * HID + j];
    }
    float d = dinv[i];
    unsigned* oa = (unsigned*)(hs1A + (size_t)i * 32);   // 64B rows, line-aligned
#pragma unroll
    for (int j = 0; j < 16; ++j) oa[j] = pk2(acc[2 * j] * d, acc[2 * j + 1] * d);
    unsigned* ob = (unsigned*)(hs1B + (size_t)i * 4);    // 8B rows
    ob[0] = pk2(acc[32] * d, acc[33] * d);
    ob[1] = pk2(acc[34] * d, 0.f);
}

// acc1 via block-per-bucket LDS accumulation; edges in chunk-major order so all
// co-resident blocks gather from the same ~2MB hs1A window (L2-resident).
__global__ __launch_bounds__(512)
void k_agg1(const unsigned* __restrict__ bkt, const int* __restrict__ gcur,
            const unsigned short* __restrict__ A, const unsigned short* __restrict__ Bf,
            float* __restrict__ acc1, int n) {
    __shared__ float acc[NPB2 * LD1];   // 56.3 KB
    int b = blockIdx.x, t = threadIdx.x;
    int base = b * NPB2;
    int nv = min(NPB2, n - base);
    int nw = nv * LD1;
    for (int i = t; i < nw; i += 512) {            // self-loop init
        int node = base + i / LD1;
        int f = i % LD1;
        float v = 0.f;
        if (f < 32) v = bf2f(A[(size_t)node * 32 + f]);
        else if (f < 35) v = bf2f(Bf[(size_t)node * 4 + (f - 32)]);
        acc[i] = v;
    }
    __syncthreads();
    int ec = gcur[b] - b * CAP2;
    if (ec > CAP2) ec = CAP2;
    const unsigned* ep = bkt + (size_t)b * CAP2;
    int g = t & 3;          // feature octet
    int es = t >> 2;        // edge slot: 128 edges per iteration
    for (int e = es; e < ec; e += 128) {
        unsigned p = ep[e];                        // 4 lanes broadcast same word
        unsigned src = p & 0x3FFFF;
        int lc = p >> 18;
        uint4 av = *(const uint4*)(A + ((size_t)src << 5) + (g << 3));
        float* d = acc + lc * LD1 + (g << 3);
        atomicAdd(d + 0, bflo(av.x)); atomicAdd(d + 1, bfhi(av.x));
        atomicAdd(d + 2, bflo(av.y)); atomicAdd(d + 3, bfhi(av.y));
        atomicAdd(d + 4, bflo(av.z)); atomicAdd(d + 5, bfhi(av.z));
        atomicAdd(d + 6, bflo(av.w)); atomicAdd(d + 7, bfhi(av.w));
        if (g == 0) {
            uint2 bv = *(const uint2*)(Bf + ((size_t)src << 2));
            float* db = acc + lc * LD1 + 32;
            atomicAdd(db + 0, bflo(bv.x)); atomicAdd(db + 1, bfhi(bv.x));
            atomicAdd(db + 2, bflo(bv.y));
        }
    }
    __syncthreads();
    float* o = acc1 + (size_t)base * LD1;
    for (int i = t; i < nw; i += 512) o[i] = acc[i];
}

// ---------- layer 2 ----------

// h = relu(acc1*dinv + b1); hs2 split: hs2a 8 feats (16B rows, 3.2MB), hs2c 2 feats (4B rows)
__global__ void k_layer2(const float* __restrict__ acc1, const float* __restrict__ dinv,
                         const float* __restrict__ b1, const float* __restrict__ W2,
                         unsigned short* __restrict__ hs2a,
                         unsigned short* __restrict__ hs2c, int n) {
    int i = blockIdx.x * blockDim.x + threadIdx.x;
    if (i >= n) return;
    float d = dinv[i];
    const float4* a = (const float4*)(acc1 + (size_t)i * LD1);
    float4 tq[9];
#pragma unroll
    for (int q = 0; q < 9; ++q) tq[q] = a[q];
    const float* tf = (const float*)tq;
    float h[HID];
#pragma unroll
    for (int k = 0; k < HID; ++k) {
        float v = tf[k] * d + b1[k];
        h[k] = v > 0.f ? v : 0.f;
    }
    float o[NCLS];
#pragma unroll
    for (int j = 0; j < NCLS; ++j) o[j] = 0.f;
#pragma unroll
    for (int k = 0; k < HID; ++k) {
#pragma unroll
        for (int j = 0; j < NCLS; ++j) o[j] += h[k] * W2[k * NCLS + j];
    }
    unsigned* da = (unsigned*)(hs2a + (size_t)i * 8);
    da[0] = pk2(o[0] * d, o[1] * d);
    da[1] = pk2(o[2] * d, o[3] * d);
    da[2] = pk2(o[4] * d, o[5] * d);
    da[3] = pk2(o[6] * d, o[7] * d);
    *(unsigned*)(hs2c + (size_t)i * 2) = pk2(o[8] * d, o[9] * d);
}

// fused: block-per-bucket LDS aggregation of hs2 (both arrays L2-resident) + log_softmax
__global__ __launch_bounds__(512)
void k_agg2o(const unsigned* __restrict__ bkt, const int* __restrict__ gcur,
             const unsigned short* __restrict__ Ha, const unsigned short* __restrict__ Hc,
             const float* __restrict__ dinv, const float* __restrict__ b2,
             float* __restrict__ out, int n) {
    __shared__ float acc[NPB2 * 12];   // 18.8 KB
    __shared__ float sb2[16];
    int b = blockIdx.x, t = threadIdx.x;
    if (t < NCLS) sb2[t] = b2[t];
    int base = b * NPB2;
    int nv = min(NPB2, n - base);
    for (int i = t; i < nv * 12; i += 512) {       // self-loop init
        int node = base + i / 12;
        int f = i % 12;
        float v = 0.f;
        if (f < 8) v = bf2f(Ha[(size_t)node * 8 + f]);
        else if (f < 10) v = bf2f(Hc[(size_t)node * 2 + (f - 8)]);
        acc[i] = v;
    }
    __syncthreads();
    int ec = gcur[b] - b * CAP2;
    if (ec > CAP2) ec = CAP2;
    const unsigned* ep = bkt + (size_t)b * CAP2;
    int g2 = t & 1;
    int es = t >> 1;        // 256 edges per iteration
    for (int e = es; e < ec; e += 256) {
        unsigned p = ep[e];
        unsigned src = p & 0x3FFFF;
        int lc = p >> 18;
        if (g2 == 0) {
            uint4 hv = *(const uint4*)(Ha + ((size_t)src << 3));
            float* d = acc + lc * 12;
            atomicAdd(d + 0, bflo(hv.x)); atomicAdd(d + 1, bfhi(hv.x));
            atomicAdd(d + 2, bflo(hv.y)); atomicAdd(d + 3, bfhi(hv.y));
            atomicAdd(d + 4, bflo(hv.z)); atomicAdd(d + 5, bfhi(hv.z));
            atomicAdd(d + 6, bflo(hv.w)); atomicAdd(d + 7, bfhi(hv.w));
        } else {
            unsigned hv = *(const unsigned*)(Hc + ((size_t)src << 1));
            float* d = acc + lc * 12 + 8;
            atomicAdd(d + 0, bflo(hv)); atomicAdd(d + 1, bfhi(hv));
        }
    }
    __syncthreads();
    for (int lc = t; lc < nv; lc += 512) {         // fused log-softmax
        int node = base + lc;
        float dn = dinv[node];
        float v[NCLS];
        float m = -1e30f;
#pragma unroll
        for (int j = 0; j < NCLS; ++j) {
            v[j] = acc[lc * 12 + j] * dn + sb2[j];
            m = fmaxf(m, v[j]);
        }
        float s = 0.f;
#pragma unroll
        for (int j = 0; j < NCLS; ++j) s += expf(v[j] - m);
        float l = logf(s) + m;
        float* o = out + (size_t)node * NCLS;
#pragma unroll
        for (int j = 0; j < NCLS; ++j) o[j] = v[j] - l;
    }
}

extern "C" void kernel_launch(void* const* d_in, const int* in_sizes, int n_in,
                              void* d_out, int out_size, void* d_ws, size_t ws_size,
                              hipStream_t stream) {
    const float* x  = (const float*)d_in[0];
    const int*   ei = (const int*)d_in[1];
    const float* W1 = (const float*)d_in[2];
    const float* b1 = (const float*)d_in[3];
    const float* W2 = (const float*)d_in[4];
    const float* b2 = (const float*)d_in[5];
    float* out = (float*)d_out;

    const int n = in_sizes[0] / F_IN;   // 200000
    const int E = in_sizes[1] / 2;      // 3200000
    const int* row = ei;
    const int* col = ei + E;

    // workspace layout (u32 words): total 62.2 MB
    unsigned*       bkt  = (unsigned*)d_ws;                // [512*6912] = 3,538,944
    int*            gcur = (int*)d_ws + 3538944;           // [1,024]
    float*          dinv = (float*)d_ws + 3539968;         // [200,000]
    unsigned short* hs1A = (unsigned short*)((unsigned*)d_ws + 3739968);   // 3.2M words, 64B-aligned
    unsigned short* hs1B = (unsigned short*)((unsigned*)d_ws + 6939968);   // 0.4M words
    float*          acc1 = (float*)d_ws + 7339968;         // [7,200,000]
    unsigned short* hs2a = (unsigned short*)((unsigned*)d_ws + 14539968);  // 0.8M words, 16B-aligned
    unsigned short* hs2c = (unsigned short*)((unsigned*)d_ws + 15339968);  // 0.2M words

    const int B = 256;
    const int nbk = (E + B * EPT - 1) / (B * EPT);         // 391

    k_initcur<<<1, 1024, 0, stream>>>(gcur);
    k_bucket<<<nbk, B, 0, stream>>>(row, col, E, gcur, bkt);
    k_sort<<<NB2, B, 0, stream>>>(bkt, gcur, dinv, n);

    k_gemm1<<<(n + B - 1) / B, B, 0, stream>>>(x, W1, dinv, hs1A, hs1B, n);
    k_agg1<<<NB2, 512, 0, stream>>>(bkt, gcur, hs1A, hs1B, acc1, n);
    k_layer2<<<(n + B - 1) / B, B, 0, stream>>>(acc1, dinv, b1, W2, hs2a, hs2c, n);
    k_agg2o<<<NB2, 512, 0, stream>>>(bkt, gcur, hs2a, hs2c, dinv, b2, out, n);
}

// Round 10
// 511.364 us; speedup vs baseline: 1.8208x; 1.8208x over previous
//
#include <hip/hip_runtime.h>

#define NN    200000
#define F_IN  128
#define HID   35
#define LD1   36     // f32 acc1 row entries (144B)
#define LD2P  16     // padded bf16 hs2 row entries (32B)
#define NCLS  10
#define NPB   256    // nodes per bucket
#define NB    782    // ceil(200000/256)
#define CAP   5120   // bucket capacity: mean 4096 + 16 sigma
#define EPT   32     // edges per thread in k_bucket
#define SLICE_W 1600000   // ushorts per 8-feature slice (200000*8)

// bf16 helpers (manual RNE)
static __device__ inline unsigned short f2bf(float f) {
    unsigned u = __float_as_uint(f);
    u = (u + 0x7FFFu + ((u >> 16) & 1u)) >> 16;
    return (unsigned short)u;
}
static __device__ inline unsigned pk2(float a, float b) {
    return (unsigned)f2bf(a) | ((unsigned)f2bf(b) << 16);
}
static __device__ inline float bf2f(unsigned short h) {
    return __uint_as_float((unsigned)h << 16);
}

// ---------- bucket build (round-8 verbatim) ----------

__global__ void k_initcur(int* __restrict__ gcur) {
    int t = threadIdx.x;
    if (t < NB) gcur[t] = t * CAP;
}

__global__ __launch_bounds__(256)
void k_bucket(const int* __restrict__ row, const int* __restrict__ col, int E,
              int* __restrict__ gcur, unsigned* __restrict__ bkt) {
    __shared__ int hist[NB];
    __shared__ int basev[NB];
    int t = threadIdx.x;
    long e0 = (long)blockIdx.x * (256 * EPT);
    for (int i = t; i < NB; i += 256) hist[i] = 0;
    __syncthreads();
    int cols[EPT];
#pragma unroll
    for (int i = 0; i < EPT; ++i) {
        long e = e0 + (long)i * 256 + t;
        if (e < E) {
            int c = col[e];
            cols[i] = c;
            atomicAdd(&hist[c >> 8], 1);
        } else cols[i] = -1;
    }
    __syncthreads();
    for (int i = t; i < NB; i += 256) {
        int h = hist[i];
        basev[i] = (h > 0) ? atomicAdd(&gcur[i], h) : 0;
        hist[i] = 0;
    }
    __syncthreads();
#pragma unroll
    for (int i = 0; i < EPT; ++i) {
        int c = cols[i];
        if (c >= 0) {
            long e = e0 + (long)i * 256 + t;
            int r = row[e];
            int b = c >> 8;
            int pos = basev[b] + atomicAdd(&hist[b], 1);
            if (pos < NB * CAP) bkt[pos] = (unsigned)r | ((unsigned)(c & 255) << 18);
        }
    }
}

__global__ __launch_bounds__(256)
void k_sort(unsigned* __restrict__ bkt, const int* __restrict__ gcur,
            int* __restrict__ obeg, int* __restrict__ oend,
            float* __restrict__ dinv, int n) {
    __shared__ unsigned est[CAP];
    __shared__ int hist[NPB];
    __shared__ int cur[NPB];
    __shared__ int sc[NPB];
    int b = blockIdx.x, t = threadIdx.x;
    int ec = gcur[b] - b * CAP;
    if (ec > CAP) ec = CAP;
    unsigned* ep = bkt + (size_t)b * CAP;
    hist[t] = 0;
    __syncthreads();
    for (int e = t; e < ec; e += 256) {
        unsigned p = ep[e];
        est[e] = p;
        atomicAdd(&hist[p >> 18], 1);
    }
    __syncthreads();
    sc[t] = hist[t];
    __syncthreads();
    for (int d = 1; d < NPB; d <<= 1) {
        int add = (t >= d) ? sc[t - d] : 0;
        __syncthreads();
        sc[t] += add;
        __syncthreads();
    }
    int excl = sc[t] - hist[t];
    cur[t] = excl;
    int i = b * NPB + t;
    if (i < n) {
        obeg[i] = b * CAP + excl;
        oend[i] = b * CAP + excl + hist[t];
        dinv[i] = rsqrtf((float)(hist[t] + 1));   // +1 self loop
    }
    __syncthreads();
    for (int e = t; e < ec; e += 256) {
        unsigned p = est[e];
        int lc = p >> 18;
        int pos = atomicAdd(&cur[lc], 1);
        ep[pos] = p & 0x3FFFF;                    // row only, node order
    }
}

// ---------- layer 1 ----------

// hs1S[p][i][0..7] = bf16(dinv[i]*(x@W1)[i][8p..8p+8]); hs1B[i][0..3] = feats 32..34
__global__ void k_gemm1(const float* __restrict__ x, const float* __restrict__ W1,
                        const float* __restrict__ dinv,
                        unsigned short* __restrict__ hs1S,
                        unsigned short* __restrict__ hs1B, int n) {
    int i = blockIdx.x * blockDim.x + threadIdx.x;
    if (i >= n) return;
    float acc[HID];
#pragma unroll
    for (int j = 0; j < HID; ++j) acc[j] = 0.f;
    const float4* xr = (const float4*)(x + (size_t)i * F_IN);
    for (int k4 = 0; k4 < F_IN / 4; ++k4) {
        float4 xv = xr[k4];
        const float* w = W1 + (size_t)(k4 * 4) * HID;
#pragma unroll
        for (int j = 0; j < HID; ++j)
            acc[j] += xv.x * w[j] + xv.y * w[HID + j] + xv.z * w[2 * HID + j] + xv.w * w[3 * HID + j];
    }
    float d = dinv[i];
#pragma unroll
    for (int p = 0; p < 4; ++p) {
        unsigned* os = (unsigned*)(hs1S + (size_t)p * SLICE_W + (size_t)i * 8);  // 16B rows
        os[0] = pk2(acc[8 * p] * d,     acc[8 * p + 1] * d);
        os[1] = pk2(acc[8 * p + 2] * d, acc[8 * p + 3] * d);
        os[2] = pk2(acc[8 * p + 4] * d, acc[8 * p + 5] * d);
        os[3] = pk2(acc[8 * p + 6] * d, acc[8 * p + 7] * d);
    }
    unsigned* ob = (unsigned*)(hs1B + (size_t)i * 4);    // 8B rows
    ob[0] = pk2(acc[32] * d, acc[33] * d);
    ob[1] = pk2(acc[34] * d, 0.f);
}

// one 8-feature slice pass: acc1[i][off..off+8) = S[i] + sum_{e->i} S[srow[e]]
// wave per node; 8 lanes/edge (f = lane&7), 8 edge slots (s = lane>>3).
__global__ void k_agg1p(const int* __restrict__ obeg, const int* __restrict__ oend,
                        const unsigned* __restrict__ srow,
                        const unsigned short* __restrict__ S,
                        float* __restrict__ acc1, int n, int off) {
    int wid = (blockIdx.x * blockDim.x + threadIdx.x) >> 6;
    int lane = threadIdx.x & 63;
    if (wid >= n) return;
    int f = lane & 7;
    int s = lane >> 3;
    int beg = obeg[wid], end = oend[wid];
    float acc = 0.f;
    for (int e = beg + s; e < end; e += 8) {
        unsigned r = srow[e];
        acc += bf2f(S[((size_t)r << 3) + f]);
    }
    acc += __shfl_xor(acc, 8);
    acc += __shfl_xor(acc, 16);
    acc += __shfl_xor(acc, 32);
    if (lane < 8) {
        acc += bf2f(S[((size_t)wid << 3) + f]);    // self loop
        acc1[(size_t)wid * LD1 + off + f] = acc;   // 32B coalesced store
    }
}

// tail pass: features 32..34 from the 1.6MB B array (4-entry rows)
__global__ void k_agg1b(const int* __restrict__ obeg, const int* __restrict__ oend,
                        const unsigned* __restrict__ srow,
                        const unsigned short* __restrict__ Bf,
                        float* __restrict__ acc1, int n) {
    int wid = (blockIdx.x * blockDim.x + threadIdx.x) >> 6;
    int lane = threadIdx.x & 63;
    if (wid >= n) return;
    int f = lane & 3;
    int s = lane >> 2;
    int beg = obeg[wid], end = oend[wid];
    float acc = 0.f;
    for (int e = beg + s; e < end; e += 16) {
        unsigned r = srow[e];
        acc += bf2f(Bf[((size_t)r << 2) + f]);
    }
    acc += __shfl_xor(acc, 4);
    acc += __shfl_xor(acc, 8);
    acc += __shfl_xor(acc, 16);
    acc += __shfl_xor(acc, 32);
    if (lane < 4) {
        acc += bf2f(Bf[((size_t)wid << 2) + f]);   // self loop (pad lane adds 0)
        acc1[(size_t)wid * LD1 + 32 + f] = acc;    // 16B store, entry 35 = 0
    }
}

// ---------- layer 2 (round-8 verbatim) ----------

__global__ void k_layer2(const float* __restrict__ acc1, const float* __restrict__ dinv,
                         const float* __restrict__ b1, const float* __restrict__ W2,
                         unsigned short* __restrict__ hs2b, int n) {
    int i = blockIdx.x * blockDim.x + threadIdx.x;
    if (i >= n) return;
    float d = dinv[i];
    const float4* a = (const float4*)(acc1 + (size_t)i * LD1);
    float4 tq[9];
#pragma unroll
    for (int q = 0; q < 9; ++q) tq[q] = a[q];
    const float* tf = (const float*)tq;
    float h[HID];
#pragma unroll
    for (int k = 0; k < HID; ++k) {
        float v = tf[k] * d + b1[k];
        h[k] = v > 0.f ? v : 0.f;
    }
    float o[NCLS];
#pragma unroll
    for (int j = 0; j < NCLS; ++j) o[j] = 0.f;
#pragma unroll
    for (int k = 0; k < HID; ++k) {
#pragma unroll
        for (int j = 0; j < NCLS; ++j) o[j] += h[k] * W2[k * NCLS + j];
    }
    unsigned* dst = (unsigned*)(hs2b + (size_t)i * LD2P);  // 32B rows
#pragma unroll
    for (int j = 0; j < 5; ++j) dst[j] = pk2(o[2 * j] * d, o[2 * j + 1] * d);
    dst[5] = 0u; dst[6] = 0u; dst[7] = 0u;
}

#define NOE 0xFFFFFFFFu
__global__ void k_agg2o(const int* __restrict__ obeg, const int* __restrict__ oend,
                        const unsigned* __restrict__ srow,
                        const unsigned short* __restrict__ H,
                        const float* __restrict__ dinv, const float* __restrict__ b2,
                        float* __restrict__ out, int n) {
    int wv = (blockIdx.x * blockDim.x + threadIdx.x) >> 6;
    int lane = threadIdx.x & 63;
    int w0 = wv * 2, w1 = w0 + 1;
    if (w0 >= n) return;
    bool has1 = (w1 < n);
    int s = lane & 15;
    int g = lane >> 4;
    bool ga = (g < 3);
    int beg0 = obeg[w0], end0 = oend[w0];
    int beg1 = has1 ? obeg[w1] : 0, end1 = has1 ? oend[w1] : 0;
    int nb0 = end0 - beg0, nb1 = end1 - beg1;
    int iters = max((nb0 + 15) >> 4, (nb1 + 15) >> 4);
    float a0=0.f,a1=0.f,a2=0.f,a3=0.f;
    float c0=0.f,c1=0.f,c2=0.f,c3=0.f;
    int e0 = beg0 + s, e1 = beg1 + s;
    for (int it = 0; it < iters; ++it) {
        unsigned idx0 = (e0 < end0) ? srow[e0] : NOE;
        unsigned idx1 = (has1 && e1 < end1) ? srow[e1] : NOE;
        bool v0 = (idx0 != NOE), v1 = (idx1 != NOE);
        unsigned r0 = v0 ? idx0 : (unsigned)w0;
        unsigned r1 = v1 ? idx1 : (unsigned)w0;
        uint2 h0 = make_uint2(0u,0u), h1 = make_uint2(0u,0u);
        if (ga) {
            h0 = *(const uint2*)(H + ((size_t)r0 << 4) + (g << 2));
            h1 = *(const uint2*)(H + ((size_t)r1 << 4) + (g << 2));
        }
        if (v0) { a0 += bf2f((unsigned short)h0.x); a1 += bf2f((unsigned short)(h0.x >> 16));
                  a2 += bf2f((unsigned short)h0.y); a3 += bf2f((unsigned short)(h0.y >> 16)); }
        if (v1) { c0 += bf2f((unsigned short)h1.x); c1 += bf2f((unsigned short)(h1.x >> 16));
                  c2 += bf2f((unsigned short)h1.y); c3 += bf2f((unsigned short)(h1.y >> 16)); }
        e0 += 16; e1 += 16;
    }
#pragma unroll
    for (int d = 1; d < 16; d <<= 1) {
        a0 += __shfl_xor(a0, d); a1 += __shfl_xor(a1, d);
        a2 += __shfl_xor(a2, d); a3 += __shfl_xor(a3, d);
        c0 += __shfl_xor(c0, d); c1 += __shfl_xor(c1, d);
        c2 += __shfl_xor(c2, d); c3 += __shfl_xor(c3, d);
    }
    float v0_=-1e30f, v1_=-1e30f, v2_=-1e30f, v3_=-1e30f;
    if (s == 0 && ga) {
        uint2 sv = *(const uint2*)(H + ((size_t)w0 << 4) + (g << 2));
        a0 += bf2f((unsigned short)sv.x); a1 += bf2f((unsigned short)(sv.x >> 16));
        a2 += bf2f((unsigned short)sv.y); a3 += bf2f((unsigned short)(sv.y >> 16));
        float dn = dinv[w0];
        int f0 = g << 2;
        v0_ = a0 * dn + b2[f0];
        v1_ = a1 * dn + b2[f0 + 1];
        if (f0 + 2 < NCLS) { v2_ = a2 * dn + b2[f0 + 2]; v3_ = a3 * dn + b2[f0 + 3]; }
    }
    float m = fmaxf(fmaxf(v0_, v1_), fmaxf(v2_, v3_));
    m = fmaxf(m, __shfl_xor(m, 16));
    m = fmaxf(m, __shfl_xor(m, 32));
    float s0 = ((v0_ > -1e29f) ? expf(v0_ - m) : 0.f) + ((v1_ > -1e29f) ? expf(v1_ - m) : 0.f)
             + ((v2_ > -1e29f) ? expf(v2_ - m) : 0.f) + ((v3_ > -1e29f) ? expf(v3_ - m) : 0.f);
    s0 += __shfl_xor(s0, 16);
    s0 += __shfl_xor(s0, 32);
    if (s == 0 && ga) {
        float l = logf(s0);
        int f0 = g << 2;
        float* o = out + (size_t)w0 * NCLS + f0;
        *(float2*)o = make_float2(v0_ - m - l, v1_ - m - l);
        if (f0 + 2 < NCLS) *(float2*)(o + 2) = make_float2(v2_ - m - l, v3_ - m - l);
    }
    if (!has1) return;
    float u0=-1e30f, u1=-1e30f, u2=-1e30f, u3=-1e30f;
    if (s == 0 && ga) {
        uint2 sv = *(const uint2*)(H + ((size_t)w1 << 4) + (g << 2));
        c0 += bf2f((unsigned short)sv.x); c1 += bf2f((unsigned short)(sv.x >> 16));
        c2 += bf2f((unsigned short)sv.y); c3 += bf2f((unsigned short)(sv.y >> 16));
        float dn = dinv[w1];
        int f0 = g << 2;
        u0 = c0 * dn + b2[f0];
        u1 = c1 * dn + b2[f0 + 1];
        if (f0 + 2 < NCLS) { u2 = c2 * dn + b2[f0 + 2]; u3 = c3 * dn + b2[f0 + 3]; }
    }
    float m1 = fmaxf(fmaxf(u0, u1), fmaxf(u2, u3));
    m1 = fmaxf(m1, __shfl_xor(m1, 16));
    m1 = fmaxf(m1, __shfl_xor(m1, 32));
    float s1 = ((u0 > -1e29f) ? expf(u0 - m1) : 0.f) + ((u1 > -1e29f) ? expf(u1 - m1) : 0.f)
             + ((u2 > -1e29f) ? expf(u2 - m1) : 0.f) + ((u3 > -1e29f) ? expf(u3 - m1) : 0.f);
    s1 += __shfl_xor(s1, 16);
    s1 += __shfl_xor(s1, 32);
    if (s == 0 && ga) {
        float l = logf(s1);
        int f0 = g << 2;
        float* o = out + (size_t)w1 * NCLS + f0;
        *(float2*)o = make_float2(u0 - m1 - l, u1 - m1 - l);
        if (f0 + 2 < NCLS) *(float2*)(o + 2) = make_float2(u2 - m1 - l, u3 - m1 - l);
    }
}

extern "C" void kernel_launch(void* const* d_in, const int* in_sizes, int n_in,
                              void* d_out, int out_size, void* d_ws, size_t ws_size,
                              hipStream_t stream) {
    const float* x  = (const float*)d_in[0];
    const int*   ei = (const int*)d_in[1];
    const float* W1 = (const float*)d_in[2];
    const float* b1 = (const float*)d_in[3];
    const float* W2 = (const float*)d_in[4];
    const float* b2 = (const float*)d_in[5];
    float* out = (float*)d_out;

    const int n = in_sizes[0] / F_IN;   // 200000
    const int E = in_sizes[1] / 2;      // 3200000
    const int* row = ei;
    const int* col = ei + E;

    // workspace (u32 words): total 61.6 MB
    unsigned*       bkt  = (unsigned*)d_ws;               // [4,003,840]
    int*            gcur = (int*)d_ws + 4003840;          // [1,024]
    int*            obeg = (int*)d_ws + 4004864;          // [200,000]
    int*            oend = (int*)d_ws + 4204864;          // [200,000]
    float*          dinv = (float*)d_ws + 4404864;        // [200,000]
    unsigned short* hs1S = (unsigned short*)((unsigned*)d_ws + 4604864);  // 4 slices x 1.6M ushorts
    unsigned short* hs1B = (unsigned short*)((unsigned*)d_ws + 7804864);  // 0.4M words
    float*          acc1 = (float*)d_ws + 8204864;        // [7,200,000]
    unsigned short* hs2b = hs1S;                          // alias: slices dead after agg1 passes

    const int B = 256;
    const int nbk = (E + B * EPT - 1) / (B * EPT);        // 391
    const int gw  = (n * 64 + B - 1) / B;                 // wave-per-node grid
    const int npair = (n + 1) / 2;

    k_initcur<<<1, 1024, 0, stream>>>(gcur);
    k_bucket<<<nbk, B, 0, stream>>>(row, col, E, gcur, bkt);
    k_sort<<<NB, B, 0, stream>>>(bkt, gcur, obeg, oend, dinv, n);

    k_gemm1<<<(n + B - 1) / B, B, 0, stream>>>(x, W1, dinv, hs1S, hs1B, n);
    for (int p = 0; p < 4; ++p)
        k_agg1p<<<gw, B, 0, stream>>>(obeg, oend, bkt,
                                      hs1S + (size_t)p * SLICE_W, acc1, n, p * 8);
    k_agg1b<<<gw, B, 0, stream>>>(obeg, oend, bkt, hs1B, acc1, n);

    k_layer2<<<(n + B - 1) / B, B, 0, stream>>>(acc1, dinv, b1, W2, hs2b, n);
    k_agg2o<<<(npair * 64 + B - 1) / B, B, 0, stream>>>(obeg, oend, bkt, hs2b, dinv, b2, out, n);
}

// Round 11
// 363.452 us; speedup vs baseline: 2.5618x; 1.4070x over previous
//
#include <hip/hip_runtime.h>

#define NN    200000
#define F_IN  128
#define HID   35
#define LD1   36     // f32 acc1 row entries (144B)
#define LD2P  16     // padded bf16 hs2 row entries (32B)
#define NCLS  10
#define NPB   256    // nodes per bucket
#define NB    782    // ceil(200000/256)
#define CAP   5120   // bucket capacity: mean 4096 + 16 sigma
#define EPT   32     // edges per thread in k_bucket
#define GN    64     // nodes per gemm1 block
#define NOE   0xFFFFFFFFu

// bf16 helpers (manual RNE)
static __device__ inline unsigned short f2bf(float f) {
    unsigned u = __float_as_uint(f);
    u = (u + 0x7FFFu + ((u >> 16) & 1u)) >> 16;
    return (unsigned short)u;
}
static __device__ inline unsigned pk2(float a, float b) {
    return (unsigned)f2bf(a) | ((unsigned)f2bf(b) << 16);
}
static __device__ inline float bflo(unsigned u) { return __uint_as_float(u << 16); }
static __device__ inline float bfhi(unsigned u) { return __uint_as_float(u & 0xFFFF0000u); }

// ---------- bucket build (round-8 verbatim) ----------

__global__ void k_initcur(int* __restrict__ gcur) {
    int t = threadIdx.x;
    if (t < NB) gcur[t] = t * CAP;
}

__global__ __launch_bounds__(256)
void k_bucket(const int* __restrict__ row, const int* __restrict__ col, int E,
              int* __restrict__ gcur, unsigned* __restrict__ bkt) {
    __shared__ int hist[NB];
    __shared__ int basev[NB];
    int t = threadIdx.x;
    long e0 = (long)blockIdx.x * (256 * EPT);
    for (int i = t; i < NB; i += 256) hist[i] = 0;
    __syncthreads();
    int cols[EPT];
#pragma unroll
    for (int i = 0; i < EPT; ++i) {
        long e = e0 + (long)i * 256 + t;
        if (e < E) {
            int c = col[e];
            cols[i] = c;
            atomicAdd(&hist[c >> 8], 1);
        } else cols[i] = -1;
    }
    __syncthreads();
    for (int i = t; i < NB; i += 256) {
        int h = hist[i];
        basev[i] = (h > 0) ? atomicAdd(&gcur[i], h) : 0;
        hist[i] = 0;
    }
    __syncthreads();
#pragma unroll
    for (int i = 0; i < EPT; ++i) {
        int c = cols[i];
        if (c >= 0) {
            long e = e0 + (long)i * 256 + t;
            int r = row[e];
            int b = c >> 8;
            int pos = basev[b] + atomicAdd(&hist[b], 1);
            if (pos < NB * CAP) bkt[pos] = (unsigned)r | ((unsigned)(c & 255) << 18);
        }
    }
}

__global__ __launch_bounds__(256)
void k_sort(unsigned* __restrict__ bkt, const int* __restrict__ gcur,
            int* __restrict__ obeg, int* __restrict__ oend,
            float* __restrict__ dinv, int n) {
    __shared__ unsigned est[CAP];
    __shared__ int hist[NPB];
    __shared__ int cur[NPB];
    __shared__ int sc[NPB];
    int b = blockIdx.x, t = threadIdx.x;
    int ec = gcur[b] - b * CAP;
    if (ec > CAP) ec = CAP;
    unsigned* ep = bkt + (size_t)b * CAP;
    hist[t] = 0;
    __syncthreads();
    for (int e = t; e < ec; e += 256) {
        unsigned p = ep[e];
        est[e] = p;
        atomicAdd(&hist[p >> 18], 1);
    }
    __syncthreads();
    sc[t] = hist[t];
    __syncthreads();
    for (int d = 1; d < NPB; d <<= 1) {
        int add = (t >= d) ? sc[t - d] : 0;
        __syncthreads();
        sc[t] += add;
        __syncthreads();
    }
    int excl = sc[t] - hist[t];
    cur[t] = excl;
    int i = b * NPB + t;
    if (i < n) {
        obeg[i] = b * CAP + excl;
        oend[i] = b * CAP + excl + hist[t];
        dinv[i] = rsqrtf((float)(hist[t] + 1));   // +1 self loop
    }
    __syncthreads();
    for (int e = t; e < ec; e += 256) {
        unsigned p = est[e];
        int lc = p >> 18;
        int pos = atomicAdd(&cur[lc], 1);
        ep[pos] = p & 0x3FFFF;                    // row only, node order
    }
}

// ---------- layer 1 ----------

// LDS-tiled coalesced gemm1: 64 nodes/block, x tile staged via contiguous float4
// loads; 4 threads per node compute 9 features each; repack via padded LDS.
__global__ __launch_bounds__(256)
void k_gemm1(const float* __restrict__ x, const float* __restrict__ W1,
             const float* __restrict__ dinv,
             unsigned short* __restrict__ hs1A,
             unsigned short* __restrict__ hs1B, int n) {
    __shared__ float xs[GN][129];   // +1 pad word per 128: kills LDS bank conflicts
    __shared__ float ha[GN][37];    // 37-stride: conflict-free feature writes
    int t = threadIdx.x;
    int base = blockIdx.x * GN;     // n = 200000 = 64*3125, exact
    const float4* xsrc = (const float4*)(x + (size_t)base * F_IN);
    for (int i = t; i < GN * 32; i += 256) {       // 2048 float4s, fully coalesced
        float4 v = xsrc[i];
        int node = i >> 5;
        int c4 = i & 31;
        *(float4*)&xs[node][c4 * 4] = v;
    }
    __syncthreads();
    int nl = t & 63;
    int q = t >> 6;
    int j0 = q * 9;
    int nj = (q == 3) ? 8 : 9;      // q3 covers features 27..34
    float acc[9];
#pragma unroll
    for (int j = 0; j < 9; ++j) acc[j] = 0.f;
    for (int k4 = 0; k4 < 32; ++k4) {
        float4 xv = *(const float4*)&xs[nl][k4 * 4];
        const float* w = W1 + (size_t)(k4 * 4) * HID + j0;   // wave-uniform -> s_load
#pragma unroll
        for (int j = 0; j < 9; ++j) {
            if (j < 8 || nj == 9)
                acc[j] += xv.x * w[j] + xv.y * w[HID + j]
                        + xv.z * w[2 * HID + j] + xv.w * w[3 * HID + j];
        }
    }
    float d = dinv[base + nl];
#pragma unroll
    for (int j = 0; j < 9; ++j)
        if (j < nj) ha[nl][j0 + j] = acc[j] * d;
    __syncthreads();
    unsigned* oa = (unsigned*)(hs1A + (size_t)base * 32);   // 64B rows
    for (int i = t; i < GN * 16; i += 256) {
        int node = i >> 4, p = i & 15;
        oa[i] = pk2(ha[node][2 * p], ha[node][2 * p + 1]);
    }
    unsigned* ob = (unsigned*)(hs1B + (size_t)base * 4);    // 8B rows
    for (int i = t; i < GN * 2; i += 256) {
        int node = i >> 1, p = i & 1;
        ob[i] = (p == 0) ? pk2(ha[node][32], ha[node][33]) : pk2(ha[node][34], 0.f);
    }
}

// ---------- agg1 (round-8 verbatim: dual-node, 16 slots, split A/B) ----------

__global__ void k_agg1(const int* __restrict__ obeg, const int* __restrict__ oend,
                       const unsigned* __restrict__ srow,
                       const unsigned short* __restrict__ A,
                       const unsigned short* __restrict__ Bf,
                       float* __restrict__ acc1, int n) {
    int wv = (blockIdx.x * blockDim.x + threadIdx.x) >> 6;
    int lane = threadIdx.x & 63;
    int w0 = wv * 2, w1 = w0 + 1;
    if (w0 >= n) return;
    bool has1 = (w1 < n);
    int s = lane & 15;
    int g = lane >> 4;
    bool bl = (lane < 16);
    int beg0 = obeg[w0], end0 = oend[w0];
    int beg1 = has1 ? obeg[w1] : 0, end1 = has1 ? oend[w1] : 0;
    int nb0 = end0 - beg0, nb1 = end1 - beg1;
    int iters = max((nb0 + 15) >> 4, (nb1 + 15) >> 4);
    float p0a=0.f,p0b=0.f,p0c=0.f,p0d=0.f,p0e=0.f,p0f=0.f,p0g=0.f,p0h=0.f;
    float p1a=0.f,p1b=0.f,p1c=0.f,p1d=0.f,p1e=0.f,p1f=0.f,p1g=0.f,p1h=0.f;
    float q0a=0.f,q0b=0.f,q0c=0.f, q1a=0.f,q1b=0.f,q1c=0.f;
    int e0 = beg0 + s, e1 = beg1 + s;
    for (int it = 0; it < iters; ++it) {
        unsigned idx0 = (e0 < end0) ? srow[e0] : NOE;
        unsigned idx1 = (has1 && e1 < end1) ? srow[e1] : NOE;
        bool v0 = (idx0 != NOE), v1 = (idx1 != NOE);
        unsigned r0 = v0 ? idx0 : (unsigned)w0;
        unsigned r1 = v1 ? idx1 : (unsigned)w0;
        uint4 av0 = *(const uint4*)(A + ((size_t)r0 << 5) + (g << 3));
        uint4 av1 = *(const uint4*)(A + ((size_t)r1 << 5) + (g << 3));
        uint2 bv0 = make_uint2(0u, 0u), bv1 = make_uint2(0u, 0u);
        if (bl) {
            bv0 = *(const uint2*)(Bf + ((size_t)r0 << 2));
            bv1 = *(const uint2*)(Bf + ((size_t)r1 << 2));
        }
        if (v0) {
            p0a += bflo(av0.x); p0b += bfhi(av0.x);
            p0c += bflo(av0.y); p0d += bfhi(av0.y);
            p0e += bflo(av0.z); p0f += bfhi(av0.z);
            p0g += bflo(av0.w); p0h += bfhi(av0.w);
            if (bl) { q0a += bflo(bv0.x); q0b += bfhi(bv0.x); q0c += bflo(bv0.y); }
        }
        if (v1) {
            p1a += bflo(av1.x); p1b += bfhi(av1.x);
            p1c += bflo(av1.y); p1d += bfhi(av1.y);
            p1e += bflo(av1.z); p1f += bfhi(av1.z);
            p1g += bflo(av1.w); p1h += bfhi(av1.w);
            if (bl) { q1a += bflo(bv1.x); q1b += bfhi(bv1.x); q1c += bflo(bv1.y); }
        }
        e0 += 16; e1 += 16;
    }
#pragma unroll
    for (int d = 1; d < 16; d <<= 1) {
        p0a += __shfl_xor(p0a, d); p0b += __shfl_xor(p0b, d);
        p0c += __shfl_xor(p0c, d); p0d += __shfl_xor(p0d, d);
        p0e += __shfl_xor(p0e, d); p0f += __shfl_xor(p0f, d);
        p0g += __shfl_xor(p0g, d); p0h += __shfl_xor(p0h, d);
        p1a += __shfl_xor(p1a, d); p1b += __shfl_xor(p1b, d);
        p1c += __shfl_xor(p1c, d); p1d += __shfl_xor(p1d, d);
        p1e += __shfl_xor(p1e, d); p1f += __shfl_xor(p1f, d);
        p1g += __shfl_xor(p1g, d); p1h += __shfl_xor(p1h, d);
        q0a += __shfl_xor(q0a, d); q0b += __shfl_xor(q0b, d); q0c += __shfl_xor(q0c, d);
        q1a += __shfl_xor(q1a, d); q1b += __shfl_xor(q1b, d); q1c += __shfl_xor(q1c, d);
    }
    if (s == 0) {
        uint4 sv0 = *(const uint4*)(A + ((size_t)w0 << 5) + (g << 3));
        p0a += bflo(sv0.x); p0b += bfhi(sv0.x);
        p0c += bflo(sv0.y); p0d += bfhi(sv0.y);
        p0e += bflo(sv0.z); p0f += bfhi(sv0.z);
        p0g += bflo(sv0.w); p0h += bfhi(sv0.w);
        float* o0 = acc1 + (size_t)w0 * LD1 + (g << 3);
        *(float4*)o0       = make_float4(p0a, p0b, p0c, p0d);
        *(float4*)(o0 + 4) = make_float4(p0e, p0f, p0g, p0h);
        if (has1) {
            uint4 sv1 = *(const uint4*)(A + ((size_t)w1 << 5) + (g << 3));
            p1a += bflo(sv1.x); p1b += bfhi(sv1.x);
            p1c += bflo(sv1.y); p1d += bfhi(sv1.y);
            p1e += bflo(sv1.z); p1f += bfhi(sv1.z);
            p1g += bflo(sv1.w); p1h += bfhi(sv1.w);
            float* o1 = acc1 + (size_t)w1 * LD1 + (g << 3);
            *(float4*)o1       = make_float4(p1a, p1b, p1c, p1d);
            *(float4*)(o1 + 4) = make_float4(p1e, p1f, p1g, p1h);
        }
    }
    if (lane == 0) {
        uint2 sb0 = *(const uint2*)(Bf + ((size_t)w0 << 2));
        q0a += bflo(sb0.x); q0b += bfhi(sb0.x); q0c += bflo(sb0.y);
        *(float4*)(acc1 + (size_t)w0 * LD1 + 32) = make_float4(q0a, q0b, q0c, 0.f);
        if (has1) {
            uint2 sb1 = *(const uint2*)(Bf + ((size_t)w1 << 2));
            q1a += bflo(sb1.x); q1b += bfhi(sb1.x); q1c += bflo(sb1.y);
            *(float4*)(acc1 + (size_t)w1 * LD1 + 32) = make_float4(q1a, q1b, q1c, 0.f);
        }
    }
}

// ---------- layer 2 (round-8 verbatim) ----------

__global__ void k_layer2(const float* __restrict__ acc1, const float* __restrict__ dinv,
                         const float* __restrict__ b1, const float* __restrict__ W2,
                         unsigned short* __restrict__ hs2b, int n) {
    int i = blockIdx.x * blockDim.x + threadIdx.x;
    if (i >= n) return;
    float d = dinv[i];
    const float4* a = (const float4*)(acc1 + (size_t)i * LD1);
    float4 tq[9];
#pragma unroll
    for (int q = 0; q < 9; ++q) tq[q] = a[q];
    const float* tf = (const float*)tq;
    float h[HID];
#pragma unroll
    for (int k = 0; k < HID; ++k) {
        float v = tf[k] * d + b1[k];
        h[k] = v > 0.f ? v : 0.f;
    }
    float o[NCLS];
#pragma unroll
    for (int j = 0; j < NCLS; ++j) o[j] = 0.f;
#pragma unroll
    for (int k = 0; k < HID; ++k) {
#pragma unroll
        for (int j = 0; j < NCLS; ++j) o[j] += h[k] * W2[k * NCLS + j];
    }
    unsigned* dst = (unsigned*)(hs2b + (size_t)i * LD2P);
#pragma unroll
    for (int j = 0; j < 5; ++j) dst[j] = pk2(o[2 * j] * d, o[2 * j + 1] * d);
    dst[5] = 0u; dst[6] = 0u; dst[7] = 0u;
}

__global__ void k_agg2o(const int* __restrict__ obeg, const int* __restrict__ oend,
                        const unsigned* __restrict__ srow,
                        const unsigned short* __restrict__ H,
                        const float* __restrict__ dinv, const float* __restrict__ b2,
                        float* __restrict__ out, int n) {
    int wv = (blockIdx.x * blockDim.x + threadIdx.x) >> 6;
    int lane = threadIdx.x & 63;
    int w0 = wv * 2, w1 = w0 + 1;
    if (w0 >= n) return;
    bool has1 = (w1 < n);
    int s = lane & 15;
    int g = lane >> 4;
    bool ga = (g < 3);
    int beg0 = obeg[w0], end0 = oend[w0];
    int beg1 = has1 ? obeg[w1] : 0, end1 = has1 ? oend[w1] : 0;
    int nb0 = end0 - beg0, nb1 = end1 - beg1;
    int iters = max((nb0 + 15) >> 4, (nb1 + 15) >> 4);
    float a0=0.f,a1=0.f,a2=0.f,a3=0.f;
    float c0=0.f,c1=0.f,c2=0.f,c3=0.f;
    int e0 = beg0 + s, e1 = beg1 + s;
    for (int it = 0; it < iters; ++it) {
        unsigned idx0 = (e0 < end0) ? srow[e0] : NOE;
        unsigned idx1 = (has1 && e1 < end1) ? srow[e1] : NOE;
        bool v0 = (idx0 != NOE), v1 = (idx1 != NOE);
        unsigned r0 = v0 ? idx0 : (unsigned)w0;
        unsigned r1 = v1 ? idx1 : (unsigned)w0;
        uint2 h0 = make_uint2(0u,0u), h1 = make_uint2(0u,0u);
        if (ga) {
            h0 = *(const uint2*)(H + ((size_t)r0 << 4) + (g << 2));
            h1 = *(const uint2*)(H + ((size_t)r1 << 4) + (g << 2));
        }
        if (v0) { a0 += bflo(h0.x); a1 += bfhi(h0.x); a2 += bflo(h0.y); a3 += bfhi(h0.y); }
        if (v1) { c0 += bflo(h1.x); c1 += bfhi(h1.x); c2 += bflo(h1.y); c3 += bfhi(h1.y); }
        e0 += 16; e1 += 16;
    }
#pragma unroll
    for (int d = 1; d < 16; d <<= 1) {
        a0 += __shfl_xor(a0, d); a1 += __shfl_xor(a1, d);
        a2 += __shfl_xor(a2, d); a3 += __shfl_xor(a3, d);
        c0 += __shfl_xor(c0, d); c1 += __shfl_xor(c1, d);
        c2 += __shfl_xor(c2, d); c3 += __shfl_xor(c3, d);
    }
    float v0_=-1e30f, v1_=-1e30f, v2_=-1e30f, v3_=-1e30f;
    if (s == 0 && ga) {
        uint2 sv = *(const uint2*)(H + ((size_t)w0 << 4) + (g << 2));
        a0 += bflo(sv.x); a1 += bfhi(sv.x); a2 += bflo(sv.y); a3 += bfhi(sv.y);
        float dn = dinv[w0];
        int f0 = g << 2;
        v0_ = a0 * dn + b2[f0];
        v1_ = a1 * dn + b2[f0 + 1];
        if (f0 + 2 < NCLS) { v2_ = a2 * dn + b2[f0 + 2]; v3_ = a3 * dn + b2[f0 + 3]; }
    }
    float m = fmaxf(fmaxf(v0_, v1_), fmaxf(v2_, v3_));
    m = fmaxf(m, __shfl_xor(m, 16));
    m = fmaxf(m, __shfl_xor(m, 32));
    float s0 = ((v0_ > -1e29f) ? expf(v0_ - m) : 0.f) + ((v1_ > -1e29f) ? expf(v1_ - m) : 0.f)
             + ((v2_ > -1e29f) ? expf(v2_ - m) : 0.f) + ((v3_ > -1e29f) ? expf(v3_ - m) : 0.f);
    s0 += __shfl_xor(s0, 16);
    s0 += __shfl_xor(s0, 32);
    if (s == 0 && ga) {
        float l = logf(s0);
        int f0 = g << 2;
        float* o = out + (size_t)w0 * NCLS + f0;
        *(float2*)o = make_float2(v0_ - m - l, v1_ - m - l);
        if (f0 + 2 < NCLS) *(float2*)(o + 2) = make_float2(v2_ - m - l, v3_ - m - l);
    }
    if (!has1) return;
    float u0=-1e30f, u1=-1e30f, u2=-1e30f, u3=-1e30f;
    if (s == 0 && ga) {
        uint2 sv = *(const uint2*)(H + ((size_t)w1 << 4) + (g << 2));
        c0 += bflo(sv.x); c1 += bfhi(sv.x); c2 += bflo(sv.y); c3 += bfhi(sv.y);
        float dn = dinv[w1];
        int f0 = g << 2;
        u0 = c0 * dn + b2[f0];
        u1 = c1 * dn + b2[f0 + 1];
        if (f0 + 2 < NCLS) { u2 = c2 * dn + b2[f0 + 2]; u3 = c3 * dn + b2[f0 + 3]; }
    }
    float m1 = fmaxf(fmaxf(u0, u1), fmaxf(u2, u3));
    m1 = fmaxf(m1, __shfl_xor(m1, 16));
    m1 = fmaxf(m1, __shfl_xor(m1, 32));
    float s1 = ((u0 > -1e29f) ? expf(u0 - m1) : 0.f) + ((u1 > -1e29f) ? expf(u1 - m1) : 0.f)
             + ((u2 > -1e29f) ? expf(u2 - m1) : 0.f) + ((u3 > -1e29f) ? expf(u3 - m1) : 0.f);
    s1 += __shfl_xor(s1, 16);
    s1 += __shfl_xor(s1, 32);
    if (s == 0 && ga) {
        float l = logf(s1);
        int f0 = g << 2;
        float* o = out + (size_t)w1 * NCLS + f0;
        *(float2*)o = make_float2(u0 - m1 - l, u1 - m1 - l);
        if (f0 + 2 < NCLS) *(float2*)(o + 2) = make_float2(u2 - m1 - l, u3 - m1 - l);
    }
}

extern "C" void kernel_launch(void* const* d_in, const int* in_sizes, int n_in,
                              void* d_out, int out_size, void* d_ws, size_t ws_size,
                              hipStream_t stream) {
    const float* x  = (const float*)d_in[0];
    const int*   ei = (const int*)d_in[1];
    const float* W1 = (const float*)d_in[2];
    const float* b1 = (const float*)d_in[3];
    const float* W2 = (const float*)d_in[4];
    const float* b2 = (const float*)d_in[5];
    float* out = (float*)d_out;

    const int n = in_sizes[0] / F_IN;   // 200000
    const int E = in_sizes[1] / 2;      // 3200000
    const int* row = ei;
    const int* col = ei + E;

    // workspace (u32 words): total 61.6 MB (round-8 layout)
    unsigned*       bkt  = (unsigned*)d_ws;               // [4,003,840]
    int*            gcur = (int*)d_ws + 4003840;          // [1,024]
    int*            obeg = (int*)d_ws + 4004864;          // [200,000]
    int*            oend = (int*)d_ws + 4204864;          // [200,000]
    float*          dinv = (float*)d_ws + 4404864;        // [200,000]
    unsigned short* hs1A = (unsigned short*)((unsigned*)d_ws + 4604864);  // 3.2M words, 64B-aligned
    unsigned short* hs1B = (unsigned short*)((unsigned*)d_ws + 7804864);  // 0.4M words
    float*          acc1 = (float*)d_ws + 8204864;        // [7,200,000]
    unsigned short* hs2b = hs1A;                          // alias: hs1A dead after agg1

    const int B = 256;
    const int nbk = (E + B * EPT - 1) / (B * EPT);        // 391
    const int npair = (n + 1) / 2;

    k_initcur<<<1, 1024, 0, stream>>>(gcur);
    k_bucket<<<nbk, B, 0, stream>>>(row, col, E, gcur, bkt);
    k_sort<<<NB, B, 0, stream>>>(bkt, gcur, obeg, oend, dinv, n);

    k_gemm1<<<(n + GN - 1) / GN, B, 0, stream>>>(x, W1, dinv, hs1A, hs1B, n);
    k_agg1<<<(npair * 64 + B - 1) / B, B, 0, stream>>>(obeg, oend, bkt, hs1A, hs1B, acc1, n);
    k_layer2<<<(n + B - 1) / B, B, 0, stream>>>(acc1, dinv, b1, W2, hs2b, n);
    k_agg2o<<<(npair * 64 + B - 1) / B, B, 0, stream>>>(obeg, oend, bkt, hs2b, dinv, b2, out, n);
}